// Round 8
// baseline (131.757 us; speedup 1.0000x reference)
//
#include <hip/hip_runtime.h>
#include <math.h>

// CRF loss: B=256, L=256, T=50. ONE WAVE per batch element, barrier-free scan.
//
// R8: single-crossing MFMA recurrence via K-permutation.
//   v'[to] = (sum_f v[f] * E2[f][to]) * ehat[to],  E2 = exp2(trans/ln2) const.
// MFMA contracts over slots; permute slots->tags: tag(slot)=(slot>>1)+32*(slot&1).
// Then A-frag reg r chunk c needs pair (v[u], v[u+32]), u=16c+4q+r, and after the
// matvec lane (q,n) holds tags {n,n+16,n+32,n+48} (reg0 of 4 n-tiles, rows equal)
// -> pairs pack LOCALLY, gather is 8 parallel ds_bpermute from lane 4q+r: ONE
// LDS crossing per step. 8 independent MFMAs (zero-C) + 1 add. Stale renorm:
// rr = rcp(v_prev[0]) computed during the bpermute wait; |log2 v| < ~50, safe.
// State: alpha = v * 2^S, S += log2(v_prev[0]) off-path.

#define TAGS 50
#define LEN 256
#define INV_LN2 1.4426950408889634f
#define LN2 0.6931471805599453f

typedef __attribute__((ext_vector_type(8))) short bf16x8;
typedef __attribute__((ext_vector_type(4))) float f32x4;

#if __has_builtin(__builtin_amdgcn_exp2f)
#define EXP2F(x) __builtin_amdgcn_exp2f(x)
#else
#define EXP2F(x) exp2f(x)
#endif
#if __has_builtin(__builtin_amdgcn_logf)
#define LOG2F(x) __builtin_amdgcn_logf(x)
#else
#define LOG2F(x) log2f(x)
#endif
#if __has_builtin(__builtin_amdgcn_rcpf)
#define RCPF(x) __builtin_amdgcn_rcpf(x)
#else
#define RCPF(x) (1.0f / (x))
#endif

__device__ __forceinline__ float readlane_f(float v, int srclane) {
  return __builtin_bit_cast(float,
      __builtin_amdgcn_readlane(__builtin_bit_cast(int, v), srclane));
}

// Pack two fp32 into one VGPR as (bf16(hi) << 16) | bf16(lo), round-half-up.
__device__ __forceinline__ int bf16pair(float lo, float hi) {
  unsigned lb = (__builtin_bit_cast(unsigned, lo) + 0x8000u) >> 16;
  unsigned hb = (__builtin_bit_cast(unsigned, hi) + 0x8000u) & 0xFFFF0000u;
  return (int)(hb | lb);
}

__global__ __launch_bounds__(64) void crf_fwd_kernel(
    const float* __restrict__ feats,   // (B, L, T)
    const float* __restrict__ trans,   // (T, T)
    const int*   __restrict__ tags,    // (B, L)
    const int*   __restrict__ mask,    // (B, L)
    float*       __restrict__ out)     // (B,)
{
  const int b    = blockIdx.x;
  const int lane = threadIdx.x;
  const int q    = lane >> 4;                         // MFMA quad
  const int n    = lane & 15;                         // MFMA col within tile

  __shared__ __align__(16) float feats_lds[LEN * TAGS]; // emits, prescaled 1/ln2
  __shared__ int mask_lds[LEN];

  const float* fb = feats + (size_t)b * (LEN * TAGS);
  const int*   tb = tags + b * LEN;
  const int*   mb = mask + b * LEN;

  // Gold-score tags into registers (latency overlaps preload).
  int tg_c[4], tg_p[4];
#pragma unroll
  for (int k = 0; k < 4; ++k) {
    const int p = lane + 64 * k;
    tg_c[k] = tb[p];
    tg_p[k] = (p >= 1) ? tb[p - 1] : 0;
  }

  // ---- Bulk preload: feats[b] (prescaled) + mask[b] ----
  {
    const float4* fv = (const float4*)fb;
    for (int i = lane; i < (LEN * TAGS) / 4; i += 64) {
      float4 v4 = fv[i];
      v4.x *= INV_LN2; v4.y *= INV_LN2; v4.z *= INV_LN2; v4.w *= INV_LN2;
      *(float4*)&feats_lds[i * 4] = v4;
    }
    for (int i = lane; i < LEN; i += 64) mask_lds[i] = mb[i];
  }

  // This lane's 4 tags (tile t -> tag n+16t); clamped index for pads.
  int tgl[4], tcl[4], vld[4];
#pragma unroll
  for (int t = 0; t < 4; ++t) {
    tgl[t] = n + 16 * t;
    vld[t] = tgl[t] < TAGS;
    tcl[t] = vld[t] ? tgl[t] : (TAGS - 1);
  }

  // ---- Constant B-frags with K-permutation: slot j at quad q, chunk c carries
  //      tag = 16c + 4q + (j>>1) + 32*(j&1); col = 16t + n; pads -> 0. ----
  union U8 { int i[4]; bf16x8 v; };
  U8 Bfr[4][2];
#pragma unroll
  for (int t = 0; t < 4; ++t)
#pragma unroll
    for (int c = 0; c < 2; ++c)
#pragma unroll
      for (int r = 0; r < 4; ++r) {
        const int col = 16 * t + n;
        const int tag0 = 16 * c + 4 * q + r;          // e = 0
        const int tag1 = tag0 + 32;                   // e = 1
        const float e0 = (tag0 < TAGS && col < TAGS)
            ? EXP2F(trans[tag0 * TAGS + col] * INV_LN2) : 0.0f;
        const float e1 = (tag1 < TAGS && col < TAGS)
            ? EXP2F(trans[tag1 * TAGS + col] * INV_LN2) : 0.0f;
        Bfr[t][c].i[r] = bf16pair(e0, e1);
      }

  // bpermute byte addresses: source lane 4q+r.
  int addr[4];
#pragma unroll
  for (int r = 0; r < 4; ++r) addr[r] = (4 * q + r) * 4;

  __syncthreads();                                    // single wave: waitcnt only

  // ---- Init: v[t] = exp2(e0[tag] - c0), pads 0; S = c0. ----
  const float c0 = feats_lds[0];                      // tag-0 emit (uniform)
  float v[4];
#pragma unroll
  for (int t = 0; t < 4; ++t)
    v[t] = vld[t] ? EXP2F(feats_lds[tcl[t]] - c0) : 0.0f;
  float S = c0;

  // ehat prefetch for l = 1.
  float eh[4];
#pragma unroll
  for (int t = 0; t < 4; ++t) eh[t] = EXP2F(feats_lds[TAGS + tcl[t]]);
  int m_nxt = mask_lds[1];

  const f32x4 zero4 = {0.0f, 0.0f, 0.0f, 0.0f};

  for (int l = 1; l < LEN; ++l) {
    const int m_cur = m_nxt;
    const int ln = (l + 1 < LEN) ? (l + 1) : (LEN - 1);

    // ---- Local pack (pairs (v[u], v[u+32]) live in one lane by construction) ----
    const int P0 = bf16pair(v[0], v[2]);              // (v[n],    v[n+32])
    const int P1 = bf16pair(v[1], v[3]);              // (v[n+16], v[n+48])

    // Stale renorm pivot: off critical path (overlaps bpermute wait).
    const float cc = readlane_f(v[0], 0);             // v_prev[tag 0] > 0
    const float rr = RCPF(cc);

    // ---- THE one crossing: 8 parallel bpermutes ----
    U8 A0, A1;
#pragma unroll
    for (int r = 0; r < 4; ++r) {
      A0.i[r] = __builtin_amdgcn_ds_bpermute(addr[r], P0);  // chunk 0
      A1.i[r] = __builtin_amdgcn_ds_bpermute(addr[r], P1);  // chunk 1
    }

    // ---- 8 independent MFMAs (4 n-tiles x 2 k-chunks), combine with adds ----
    f32x4 d0 = __builtin_amdgcn_mfma_f32_16x16x32_bf16(A0.v, Bfr[0][0].v, zero4, 0, 0, 0);
    f32x4 d1 = __builtin_amdgcn_mfma_f32_16x16x32_bf16(A0.v, Bfr[1][0].v, zero4, 0, 0, 0);
    f32x4 d2 = __builtin_amdgcn_mfma_f32_16x16x32_bf16(A0.v, Bfr[2][0].v, zero4, 0, 0, 0);
    f32x4 d3 = __builtin_amdgcn_mfma_f32_16x16x32_bf16(A0.v, Bfr[3][0].v, zero4, 0, 0, 0);
    f32x4 g0 = __builtin_amdgcn_mfma_f32_16x16x32_bf16(A1.v, Bfr[0][1].v, zero4, 0, 0, 0);
    f32x4 g1 = __builtin_amdgcn_mfma_f32_16x16x32_bf16(A1.v, Bfr[1][1].v, zero4, 0, 0, 0);
    f32x4 g2 = __builtin_amdgcn_mfma_f32_16x16x32_bf16(A1.v, Bfr[2][1].v, zero4, 0, 0, 0);
    f32x4 g3 = __builtin_amdgcn_mfma_f32_16x16x32_bf16(A1.v, Bfr[3][1].v, zero4, 0, 0, 0);

    // ---- ehat prefetch for l+1 (off critical path, overlaps MFMA) ----
    float ehn[4];
#pragma unroll
    for (int t = 0; t < 4; ++t) ehn[t] = feats_lds[ln * TAGS + tcl[t]];
    const int m_n2 = mask_lds[ln];

    // ---- Tail: combine, emit-scale, mask, renorm (elementwise, 4 tags/lane) ----
    const float f0 = d0[0] + g0[0];
    const float f1 = d1[0] + g1[0];
    const float f2 = d2[0] + g2[0];
    const float f3 = d3[0] + g3[0];
    v[0] = ((m_cur > 0) ? f0 * eh[0] : v[0]) * rr;
    v[1] = ((m_cur > 0) ? f1 * eh[1] : v[1]) * rr;
    v[2] = ((m_cur > 0) ? f2 * eh[2] : v[2]) * rr;
    v[3] = ((m_cur > 0) ? f3 * eh[3] : v[3]) * rr;
    S += LOG2F(cc);                                   // off-path scalar-ish
#pragma unroll
    for (int t = 0; t < 4; ++t) eh[t] = EXP2F(ehn[t]);
    m_nxt = m_n2;
  }

  // ---- Final logsumexp: pads are 0; quads hold replicas -> reduce 16 cols ----
  float vsum = (v[0] + v[1]) + (v[2] + v[3]);
#pragma unroll
  for (int off = 8; off; off >>= 1) vsum += __shfl_xor(vsum, off, 64);
  // lane with n==0 in each quad now holds the full sum over all 64 tags.

  // ---- Gold score: lane handles positions lane, +64, +128, +192 ----
  float gp = 0.0f;
#pragma unroll
  for (int k = 0; k < 4; ++k) {
    const int p = lane + 64 * k;
    if (mask_lds[p] > 0) {
      float vv = feats_lds[p * TAGS + tg_c[k]] * LN2; // un-prescale
      if (p >= 1) vv += trans[tg_p[k] * TAGS + tg_c[k]];
      gp += vv;
    }
  }
#pragma unroll
  for (int off = 32; off; off >>= 1) gp += __shfl_xor(gp, off, 64);

  if (lane == 0) {
    const float all_path = LN2 * (S + LOG2F(vsum));
    out[b] = all_path - gp;
  }
}

extern "C" void kernel_launch(void* const* d_in, const int* in_sizes, int n_in,
                              void* d_out, int out_size, void* d_ws, size_t ws_size,
                              hipStream_t stream) {
  const float* feats = (const float*)d_in[0];
  const float* trans = (const float*)d_in[1];
  const int*   tags  = (const int*)d_in[2];
  const int*   mask  = (const int*)d_in[3];
  float* out = (float*)d_out;

  const int B = out_size;  // 256
  crf_fwd_kernel<<<B, 64, 0, stream>>>(feats, trans, tags, mask, out);
}